// Round 7
// baseline (68.779 us; speedup 1.0000x reference)
//
#include <hip/hip_runtime.h>

// Problem geometry (fixed by reference setup_inputs)
#define B   4
#define D   48
#define H   128
#define W   240
#define H4  512   // 4*H
#define W4  960   // 4*W
#define DSPLIT 2
#define DPART  (D / DSPLIT)
#define NPIX   (B * H * W)        // 122880 coarse pixels
#define NBLK   1920               // grid; block i owns A-chunk i (64 px) + B-slice i (256 items)
#define CHPX   64                 // coarse pixels per A-chunk
#define MAGIC  0x5EED1234u
#define SPIN_MAX (1 << 15)

// register-light exact recompute (fallback path only; identical arithmetic)
__device__ float serial_disp(const float* __restrict__ cost, int b, int y, int x) {
    const float* p = cost + (size_t)b * (D * H * W) + y * W + x;
    float v1 = -INFINITY, v2 = -INFINITY;
    int   i1 = 0,          i2 = 0;
    for (int d = 0; d < D; ++d) {
        float v = p[(size_t)d * (H * W)];
        if (v > v1)      { v2 = v1; i2 = i1; v1 = v; i1 = d; }
        else if (v > v2) { v2 = v;  i2 = d; }
    }
    float e = expf(v2 - v1);
    return ((float)i1 + (float)i2 * e) / (1.0f + e);
}

// Single-dispatch fused kernel with per-chunk producer flags.
// Phase A: block i computes disp4[64i .. 64i+64) (2 thr/px, shfl-merged top-2),
//          publishes via agent-scope stores, sets flags[i]=MAGIC (release).
// Phase B: block i handles output items t in [256i, 256i+256); spin-waits
//          (acquire) on the <=16 chunk flags covering its 3-coarse-row halo.
// All 1920 blocks are co-resident (launch_bounds(256,8) => VGPR<=64 => 8 blk/CU
// capacity = 2048 >= 1920), so producers always run: no dispatch-order hazard.
// Timeout fallback recomputes directly (same values) -> deadlock-impossible.
__global__ void __launch_bounds__(256, 8)
fused_flag_kernel(const float* __restrict__ cost, const float* __restrict__ spg,
                  float* __restrict__ out, float* __restrict__ ws) {
    float*    disp4 = ws;                       // [NPIX] floats
    unsigned* flags = (unsigned*)(ws + NPIX);   // [NBLK] u32

    const int blk = blockIdx.x;
    const int tid = threadIdx.x;

    // ---------------- Phase A: 64 px x 2 halves = 128 threads ----------------
    if (tid < CHPX * DSPLIT) {
        int pix  = blk * CHPX + (tid >> 1);
        int half = tid & 1;
        int b    = pix / (H * W);
        int rem  = pix - b * (H * W);
        const float* p = cost + (size_t)b * (D * H * W)
                              + (size_t)(half * DPART) * (H * W) + rem;

        float v[DPART];
        #pragma unroll
        for (int d = 0; d < DPART; ++d) v[d] = p[(size_t)d * (H * W)];

        float v1 = -INFINITY, v2 = -INFINITY;
        int   i1 = 0,          i2 = 0;
        const int d0 = half * DPART;
        #pragma unroll
        for (int d = 0; d < DPART; ++d) {
            float x = v[d];
            if (x > v1)      { v2 = v1; i2 = i1; v1 = x; i1 = d0 + d; }
            else if (x > v2) { v2 = x;  i2 = d0 + d; }
        }

        float pv1 = __shfl_xor(v1, 1);
        int   pi1 = __shfl_xor(i1, 1);
        float pv2 = __shfl_xor(v2, 1);
        int   pi2 = __shfl_xor(i2, 1);

        float av1, av2, bv1, bv2; int ai1, ai2, bi1, bi2;
        if (half == 0) { av1=v1;  ai1=i1;  av2=v2;  ai2=i2;  bv1=pv1; bi1=pi1; bv2=pv2; bi2=pi2; }
        else           { av1=pv1; ai1=pi1; av2=pv2; ai2=pi2; bv1=v1;  bi1=i1;  bv2=v2;  bi2=i2; }

        float t1v, t2v; int t1i, t2i;
        if (bv1 > av1) {
            t1v = bv1; t1i = bi1;
            if (av1 >= bv2) { t2v = av1; t2i = ai1; } else { t2v = bv2; t2i = bi2; }
        } else {
            t1v = av1; t1i = ai1;
            if (av2 >= bv1) { t2v = av2; t2i = ai2; } else { t2v = bv1; t2i = bi1; }
        }

        if (half == 0) {
            float e = expf(t2v - t1v);
            float dres = ((float)t1i + (float)t2i * e) / (1.0f + e);
            __hip_atomic_store(&disp4[pix], dres, __ATOMIC_RELAXED,
                               __HIP_MEMORY_SCOPE_AGENT);
        }
    }
    __syncthreads();   // vmcnt(0) drain: all chunk stores agent-visible
    if (tid == 0)
        __hip_atomic_store(&flags[blk], MAGIC, __ATOMIC_RELEASE,
                           __HIP_MEMORY_SCOPE_AGENT);

    // ---------------- Phase B dependency wait ----------------
    const int t  = blk * 256 + tid;          // < 491520 exactly
    int xs  = t % W;
    int tmp = t / W;
    int Y   = tmp % H4;
    int b   = tmp / H4;
    int y   = Y >> 2;

    // chunk range covering this block's 3-coarse-row halo (blocks never straddle batches)
    __shared__ int s_timeout;
    if (tid == 0) s_timeout = 0;
    {
        int t0 = blk * 256, t1 = t0 + 255;
        int m0 = t0 / W, m1 = t1 / W;
        int b0 = m0 / H4, b1 = m1 / H4;
        int ylo = (m0 % H4) / 4 - 1; if (ylo < 0) ylo = 0;
        int yhi = (m1 % H4) / 4 + 1; if (yhi > H - 1) yhi = H - 1;
        int c0 = ((b0 * H + ylo) * W) / CHPX;
        int c1 = ((b1 * H + yhi) * W + (W - 1)) / CHPX;
        __syncthreads();                     // s_timeout=0 visible
        int nf = c1 - c0 + 1;                // <= 16
        if (tid < nf) {
            const unsigned* f = &flags[c0 + tid];
            int it = 0;
            while (__hip_atomic_load(f, __ATOMIC_ACQUIRE,
                                     __HIP_MEMORY_SCOPE_AGENT) != MAGIC) {
                if (++it > SPIN_MAX) { s_timeout = 1; break; }
                __builtin_amdgcn_s_sleep(8);
            }
        }
        __syncthreads();
    }
    const bool direct = (s_timeout != 0);

    // ---------------- Phase B: upfeat ----------------
    float dv[9];
    const float* dp = disp4 + (size_t)b * (H * W);
    #pragma unroll
    for (int dy = 0; dy < 3; ++dy) {
        int yy = y + dy - 1;
        #pragma unroll
        for (int dx = 0; dx < 3; ++dx) {
            int xx = xs + dx - 1;
            float val = 0.0f;
            if ((unsigned)yy < H && (unsigned)xx < W) {
                val = direct ? serial_disp(cost, b, yy, xx)
                             : __hip_atomic_load(&dp[yy * W + xx], __ATOMIC_RELAXED,
                                                 __HIP_MEMORY_SCOPE_AGENT);
            }
            dv[dy * 3 + dx] = val;
        }
    }

    const float* sp = spg + (((size_t)b * 9) * H4 + Y) * W4 + 4 * xs;
    float4 acc = make_float4(0.f, 0.f, 0.f, 0.f);
    #pragma unroll
    for (int k = 0; k < 9; ++k) {
        float4 s = *reinterpret_cast<const float4*>(sp + (size_t)k * (H4 * W4));
        float  d = dv[k];
        acc.x += d * s.x; acc.y += d * s.y; acc.z += d * s.z; acc.w += d * s.w;
    }
    acc.x *= 4.f; acc.y *= 4.f; acc.z *= 4.f; acc.w *= 4.f;

    *reinterpret_cast<float4*>(out + ((size_t)b * H4 + Y) * W4 + 4 * xs) = acc;
}

extern "C" void kernel_launch(void* const* d_in, const int* in_sizes, int n_in,
                              void* d_out, int out_size, void* d_ws, size_t ws_size,
                              hipStream_t stream) {
    const float* cost = (const float*)d_in[0];   // [B,1,D,H,W]
    const float* spg  = (const float*)d_in[1];   // [B,9,H4,W4]
    float* outp = (float*)d_out;                 // [B,H4,W4]
    float* ws   = (float*)d_ws;                  // disp4 (491520 B) + flags (7680 B)

    fused_flag_kernel<<<NBLK, 256, 0, stream>>>(cost, spg, outp, ws);
}

// Round 8
// 40.048 us; speedup vs baseline: 1.7174x; 1.7174x over previous
//
#include <hip/hip_runtime.h>

// Problem geometry (fixed by reference setup_inputs)
#define B   4
#define D   48
#define H   128
#define W   240
#define H4  512   // 4*H
#define W4  960   // 4*W
#define DPART  (D / 2)            // 24 d-slices per wave-pair half
#define NPIX   (B * H * W)        // 122880 coarse pixels
#define CHPX   128                // coarse pixels per chunk (= per block)
#define NBLK   (NPIX / CHPX)      // 960 blocks; 240 per batch (no batch straddle)
#define CPB    (H * W / CHPX)     // 240 chunks per batch
#define MAGIC  0x5EED1234u
#define SPIN_MAX (1 << 15)

// register-light exact recompute (timeout fallback only; identical arithmetic)
__device__ float serial_disp(const float* __restrict__ cost, int b, int y, int x) {
    const float* p = cost + (size_t)b * (D * H * W) + y * W + x;
    float v1 = -INFINITY, v2 = -INFINITY;
    int   i1 = 0,          i2 = 0;
    for (int d = 0; d < D; ++d) {
        float v = p[(size_t)d * (H * W)];
        if (v > v1)      { v2 = v1; i2 = i1; v1 = v; i1 = d; }
        else if (v > v2) { v2 = v;  i2 = d; }
    }
    float e = expf(v2 - v1);
    return ((float)i1 + (float)i2 * e) / (1.0f + e);
}

// Single-dispatch fused producer/consumer kernel.
// Phase A: block i computes disp4 for chunk i (128 px). Waves 0-1 take d[0,24),
//   waves 2-3 take d[24,48) (fully coalesced 256B/wave loads, 24-deep ILP),
//   merge via LDS, publish with agent-scope stores, release flags[i]=MAGIC.
// Phase B: block i produces output items [512i, 512i+512) (2 per thread),
//   spin-waiting (acquire) only on the <=10 chunk flags its 3-row halo needs.
// Co-residency: launch_bounds(256,4) => VGPR cap 128 (v[24] stays in regs,
//   the R7 failure was a 64-cap spill) and 4 blk/CU * 256 CU = 1024 >= 960,
//   so all producers run concurrently: no dispatch-order hazard. Timeout
//   fallback recomputes identical values -> deadlock-impossible.
__global__ void __launch_bounds__(256, 4)
fused_flag_kernel(const float* __restrict__ cost, const float* __restrict__ spg,
                  float* __restrict__ out, float* __restrict__ ws) {
    float*    disp4 = ws;                       // [NPIX] floats
    unsigned* flags = (unsigned*)(ws + NPIX);   // [NBLK] u32

    const int blk = blockIdx.x;
    const int tid = threadIdx.x;

    __shared__ float4 smrg[CHPX];   // half-1 top-2 lists
    __shared__ int    s_timeout;

    // ---------------- Phase A ----------------
    {
        int half = tid >> 7;                    // waves 0-1: half 0, waves 2-3: half 1
        int poff = tid & (CHPX - 1);
        int pix  = blk * CHPX + poff;           // global coarse pixel (row-major)
        int b    = blk / CPB;
        const float* p = cost + (size_t)b * (D * H * W)
                              + (size_t)(half * DPART) * (H * W)
                              + (pix - b * (H * W));

        float v[DPART];
        #pragma unroll
        for (int d = 0; d < DPART; ++d) v[d] = p[(size_t)d * (H * W)];

        float v1 = -INFINITY, v2 = -INFINITY;
        int   i1 = 0,          i2 = 0;
        const int d0 = half * DPART;
        #pragma unroll
        for (int d = 0; d < DPART; ++d) {
            float x = v[d];
            if (x > v1)      { v2 = v1; i2 = i1; v1 = x; i1 = d0 + d; }
            else if (x > v2) { v2 = x;  i2 = d0 + d; }
        }

        if (half == 1)
            smrg[poff] = make_float4(v1, __int_as_float(i1), v2, __int_as_float(i2));
        if (tid == 0) s_timeout = 0;
        __syncthreads();

        if (half == 0) {
            float4 q  = smrg[poff];
            float bv1 = q.x, bv2 = q.z;
            int   bi1 = __float_as_int(q.y), bi2 = __float_as_int(q.w);
            // a = low-index half (in regs), b = high half (LDS); ties -> low index
            float t1v, t2v; int t1i, t2i;
            if (bv1 > v1) {
                t1v = bv1; t1i = bi1;
                if (v1 >= bv2) { t2v = v1; t2i = i1; } else { t2v = bv2; t2i = bi2; }
            } else {
                t1v = v1; t1i = i1;
                if (v2 >= bv1) { t2v = v2; t2i = i2; } else { t2v = bv1; t2i = bi1; }
            }
            float e = expf(t2v - t1v);
            float dres = ((float)t1i + (float)t2i * e) / (1.0f + e);
            __hip_atomic_store(&disp4[pix], dres, __ATOMIC_RELAXED,
                               __HIP_MEMORY_SCOPE_AGENT);
        }
    }
    __syncthreads();   // all chunk stores complete (vmcnt drained per wave)
    if (tid == 0)
        __hip_atomic_store(&flags[blk], MAGIC, __ATOMIC_RELEASE,
                           __HIP_MEMORY_SCOPE_AGENT);

    // ---------------- Phase B dependency wait ----------------
    {
        int t0 = blk * 512, t1 = t0 + 511;
        int m0 = t0 / W, m1 = t1 / W;           // fine-row indices (b*H4 + Y)
        int b0 = m0 / H4;
        int ylo = (m0 % H4) / 4 - 1; if (ylo < 0) ylo = 0;
        int yhi = (m1 % H4) / 4 + 1; if (yhi > H - 1) yhi = H - 1;
        int c0 = ((b0 * H + ylo) * W) / CHPX;
        int c1 = ((b0 * H + yhi) * W + (W - 1)) / CHPX;
        int nf = c1 - c0 + 1;                   // <= ~10 (single wave spins)
        if (tid < nf) {
            const unsigned* f = &flags[c0 + tid];
            int it = 0;
            while (__hip_atomic_load(f, __ATOMIC_ACQUIRE,
                                     __HIP_MEMORY_SCOPE_AGENT) != MAGIC) {
                if (++it > SPIN_MAX) { s_timeout = 1; break; }
                __builtin_amdgcn_s_sleep(2);
            }
        }
        __syncthreads();
    }
    const bool direct = (s_timeout != 0);

    // ---------------- Phase B: upfeat, 2 items per thread ----------------
    #pragma unroll
    for (int rep = 0; rep < 2; ++rep) {
        int t   = blk * 512 + rep * 256 + tid;
        int xs  = t % W;
        int tmp = t / W;
        int Y   = tmp % H4;
        int b   = tmp / H4;
        int y   = Y >> 2;

        float dv[9];
        const float* dp = disp4 + (size_t)b * (H * W);
        #pragma unroll
        for (int dy = 0; dy < 3; ++dy) {
            int yy = y + dy - 1;
            #pragma unroll
            for (int dx = 0; dx < 3; ++dx) {
                int xx = xs + dx - 1;
                float val = 0.0f;
                if ((unsigned)yy < H && (unsigned)xx < W) {
                    val = direct ? serial_disp(cost, b, yy, xx)
                                 : __hip_atomic_load(&dp[yy * W + xx], __ATOMIC_RELAXED,
                                                     __HIP_MEMORY_SCOPE_AGENT);
                }
                dv[dy * 3 + dx] = val;
            }
        }

        const float* sp = spg + (((size_t)b * 9) * H4 + Y) * W4 + 4 * xs;
        float4 acc = make_float4(0.f, 0.f, 0.f, 0.f);
        #pragma unroll
        for (int k = 0; k < 9; ++k) {
            float4 s = *reinterpret_cast<const float4*>(sp + (size_t)k * (H4 * W4));
            float  d = dv[k];
            acc.x += d * s.x; acc.y += d * s.y; acc.z += d * s.z; acc.w += d * s.w;
        }
        acc.x *= 4.f; acc.y *= 4.f; acc.z *= 4.f; acc.w *= 4.f;

        *reinterpret_cast<float4*>(out + ((size_t)b * H4 + Y) * W4 + 4 * xs) = acc;
    }
}

extern "C" void kernel_launch(void* const* d_in, const int* in_sizes, int n_in,
                              void* d_out, int out_size, void* d_ws, size_t ws_size,
                              hipStream_t stream) {
    const float* cost = (const float*)d_in[0];   // [B,1,D,H,W]
    const float* spg  = (const float*)d_in[1];   // [B,9,H4,W4]
    float* outp = (float*)d_out;                 // [B,H4,W4]
    float* ws   = (float*)d_ws;                  // disp4 (491520 B) + flags (3840 B)

    fused_flag_kernel<<<NBLK, 256, 0, stream>>>(cost, spg, outp, ws);
}

// Round 9
// 26.105 us; speedup vs baseline: 2.6347x; 1.5341x over previous
//
#include <hip/hip_runtime.h>

// Problem geometry (fixed by reference setup_inputs)
#define B   4
#define D   48
#define H   128
#define W   240
#define H4  512   // 4*H
#define W4  960   // 4*W
#define HW  (H * W)
#define NPIX (B * HW)      // 122880
#define DQ  (D / 4)        // 12 d-slices per lane quarter

// Kernel 1: top-2 soft-argmax, float4 edition.
// Lane group of 4 (consecutive lanes) owns 4 consecutive pixels; lane q holds
// d in [12q, 12q+12). 12 float4 loads/thread (fully coalesced, 12-deep ILP),
// per-pixel streaming top-2, then 2-step shfl_xor butterfly merge (lowest-index
// tie-break preserved: lower lane == lower d range). Lane q==0 stores float4.
// VMEM: 1.47M float4 loads + 30K stores (vs 5.9M scalar loads before).
__global__ void __launch_bounds__(256)
topk_softargmax_kernel(const float* __restrict__ cost, float* __restrict__ disp4) {
    int gid  = blockIdx.x * 256 + threadIdx.x;     // 0 .. NPIX-1
    int q    = gid & 3;                            // d-quarter
    int pix0 = (gid >> 2) * 4;                     // base pixel of the quad
    int b    = pix0 / HW;
    int rem  = pix0 - b * HW;
    const float* p = cost + (size_t)b * (D * HW) + (size_t)(q * DQ) * HW + rem;

    float4 vv[DQ];
    #pragma unroll
    for (int j = 0; j < DQ; ++j)
        vv[j] = *reinterpret_cast<const float4*>(p + (size_t)j * HW);

    float v1[4], v2[4]; int i1[4], i2[4];
    #pragma unroll
    for (int c = 0; c < 4; ++c) { v1[c] = -INFINITY; v2[c] = -INFINITY; i1[c] = 0; i2[c] = 0; }

    #pragma unroll
    for (int j = 0; j < DQ; ++j) {
        int d = q * DQ + j;
        float xs[4] = { vv[j].x, vv[j].y, vv[j].z, vv[j].w };
        #pragma unroll
        for (int c = 0; c < 4; ++c) {
            float x = xs[c];
            if (x > v1[c])      { v2[c] = v1[c]; i2[c] = i1[c]; v1[c] = x; i1[c] = d; }
            else if (x > v2[c]) { v2[c] = x;  i2[c] = d; }
        }
    }

    // butterfly merge across the 4-lane group (masks 1 then 2)
    #pragma unroll
    for (int step = 1; step <= 2; step <<= 1) {
        bool lower = (q & step) == 0;              // my list has the lower d range
        #pragma unroll
        for (int c = 0; c < 4; ++c) {
            float pv1 = __shfl_xor(v1[c], step);
            int   pi1 = __shfl_xor(i1[c], step);
            float pv2 = __shfl_xor(v2[c], step);
            int   pi2 = __shfl_xor(i2[c], step);
            float av1, av2, bv1, bv2; int ai1, ai2, bi1, bi2;
            if (lower) { av1=v1[c]; ai1=i1[c]; av2=v2[c]; ai2=i2[c]; bv1=pv1; bi1=pi1; bv2=pv2; bi2=pi2; }
            else       { av1=pv1;   ai1=pi1;   av2=pv2;   ai2=pi2;   bv1=v1[c]; bi1=i1[c]; bv2=v2[c]; bi2=i2[c]; }
            if (bv1 > av1) {        // top1 from high-d list
                v1[c] = bv1; i1[c] = bi1;
                if (av1 >= bv2) { v2[c] = av1; i2[c] = ai1; } else { v2[c] = bv2; i2[c] = bi2; }
            } else {                // ties -> low index
                v1[c] = av1; i1[c] = ai1;
                if (av2 >= bv1) { v2[c] = av2; i2[c] = ai2; } else { v2[c] = bv1; i2[c] = bi1; }
            }
        }
    }

    if (q == 0) {
        float4 r;
        { float e = expf(v2[0]-v1[0]); r.x = ((float)i1[0] + (float)i2[0]*e) / (1.0f+e); }
        { float e = expf(v2[1]-v1[1]); r.y = ((float)i1[1] + (float)i2[1]*e) / (1.0f+e); }
        { float e = expf(v2[2]-v1[2]); r.z = ((float)i1[2] + (float)i2[2]*e) / (1.0f+e); }
        { float e = expf(v2[3]-v1[3]); r.w = ((float)i1[3] + (float)i2[3]*e) / (1.0f+e); }
        *reinterpret_cast<float4*>(disp4 + pix0) = r;
    }
}

// Kernel 2: upfeat with LDS-staged disp4 halo.
// Block = 16x8 coarse tile; 180-value halo loaded once (plain cached loads),
// then 512 float4 outputs (2 per thread): 9 LDS reads + 9 spg float4 + 1 store.
// VMEM/block: 180 + 18*256 + 2*256 ~ removes the 9-scalar-gather per output.
#define TSX 16
#define TSY 8
__global__ void __launch_bounds__(256)
upfeat_tile_kernel(const float* __restrict__ disp4, const float* __restrict__ spg,
                   float* __restrict__ out) {
    __shared__ float sd[TSY + 2][TSX + 3];         // 10 x 19

    int blk = blockIdx.x;
    int txt = blk % (W / TSX);
    int rem = blk / (W / TSX);
    int tyt = rem % (H / TSY);
    int b   = rem / (H / TSY);
    int x0  = txt * TSX;
    int y0  = tyt * TSY;

    int i = threadIdx.x;
    if (i < (TSY + 2) * (TSX + 2)) {               // 180 halo values
        int hy = i / (TSX + 2);
        int hx = i - hy * (TSX + 2);
        int y  = y0 + hy - 1;
        int x  = x0 + hx - 1;
        float v = 0.0f;                            // zero-pad outside image
        if ((unsigned)y < H && (unsigned)x < W)
            v = disp4[(size_t)b * HW + y * W + x];
        sd[hy][hx] = v;
    }
    __syncthreads();

    int fx4 = threadIdx.x & (TSX - 1);             // float4 col == local coarse x
    int fyb = threadIdx.x >> 4;                    // 0..15

    #pragma unroll
    for (int rep = 0; rep < 2; ++rep) {
        int fy = fyb + rep * 16;                   // fine row in tile, 0..31
        int cy = fy >> 2;                          // local coarse y, 0..7
        float dv[9];
        #pragma unroll
        for (int dy = 0; dy < 3; ++dy)
            #pragma unroll
            for (int dx = 0; dx < 3; ++dx)
                dv[dy * 3 + dx] = sd[cy + dy][fx4 + dx];

        int Y  = y0 * 4 + fy;                      // global fine row
        int X4 = x0 + fx4;                         // global float4 column
        const float* sp = spg + ((size_t)(b * 9) * H4 + Y) * W4 + X4 * 4;
        float4 acc = make_float4(0.f, 0.f, 0.f, 0.f);
        #pragma unroll
        for (int k = 0; k < 9; ++k) {
            float4 s = *reinterpret_cast<const float4*>(sp + (size_t)k * (H4 * W4));
            float  d = dv[k];
            acc.x += d * s.x; acc.y += d * s.y; acc.z += d * s.z; acc.w += d * s.w;
        }
        acc.x *= 4.f; acc.y *= 4.f; acc.z *= 4.f; acc.w *= 4.f;
        *reinterpret_cast<float4*>(out + ((size_t)b * H4 + Y) * W4 + X4 * 4) = acc;
    }
}

extern "C" void kernel_launch(void* const* d_in, const int* in_sizes, int n_in,
                              void* d_out, int out_size, void* d_ws, size_t ws_size,
                              hipStream_t stream) {
    const float* cost = (const float*)d_in[0];   // [B,1,D,H,W]
    const float* spg  = (const float*)d_in[1];   // [B,9,H4,W4]
    float* outp  = (float*)d_out;                // [B,H4,W4]
    float* disp4 = (float*)d_ws;                 // [B,H,W] scratch (491 KB)

    {
        const int n = NPIX;                      // 122880 threads, 480 blocks
        topk_softargmax_kernel<<<(n + 255) / 256, 256, 0, stream>>>(cost, disp4);
    }
    {
        const int nblk = (W / TSX) * (H / TSY) * B;   // 960 blocks
        upfeat_tile_kernel<<<nblk, 256, 0, stream>>>(disp4, spg, outp);
    }
}